// Round 3
// baseline (1128.252 us; speedup 1.0000x reference)
//
#include <hip/hip_runtime.h>

typedef unsigned short u16;
typedef unsigned int u32;
typedef u16 u16x8 __attribute__((ext_vector_type(8)));
typedef short s16x8 __attribute__((ext_vector_type(8)));
typedef float f32x4 __attribute__((ext_vector_type(4)));

#define NN 32768
#define EE 262144
#define DD 512

__device__ __forceinline__ float b2f(u16 u) {
    return __uint_as_float(((u32)u) << 16);
}
__device__ __forceinline__ u16 f2b(float f) {
    u32 u = __float_as_uint(f);
    u32 r = (u + 0x7FFFu + ((u >> 16) & 1u)) >> 16;
    return (u16)r;
}

// -------- edge-index width detection: int64 (high words zero) vs int32 ------------------
__global__ void detect_kernel(const u32* __restrict__ ei, int* __restrict__ flags) {
    if (threadIdx.x == 0) {
        int allzero = 1;
        for (int i = 0; i < 64; ++i)
            if (ei[2 * i + 1] != 0u) allzero = 0;
        flags[0] = allzero;  // 1 => int64 layout
    }
}

__global__ void edges_kernel(const u32* __restrict__ ei, const int* __restrict__ flags,
                             int* __restrict__ s32, int* __restrict__ d32) {
    int t = blockIdx.x * 256 + threadIdx.x;
    u32 s, d;
    if (flags[0]) {  // int64: src at u32[2t], dst at u32[2*EE + 2t]
        s = ei[2 * t];
        d = ei[2 * EE + 2 * t];
    } else {         // int32
        s = ei[t];
        d = ei[EE + t];
    }
    s32[t] = (int)(s & (NN - 1));   // clamp: in-bounds even if misdetected
    d32[t] = (int)(d & (NN - 1));
}

// -------- fp32 x -> bf16 xb --------------------------------------------------------------
__global__ void convert_kernel(const float* __restrict__ x, u16* __restrict__ xb) {
    int t = blockIdx.x * 256 + threadIdx.x;
    f32x4 a = ((const f32x4*)x)[t * 2];
    f32x4 b = ((const f32x4*)x)[t * 2 + 1];
    u16x8 o;
    o[0] = f2b(a[0]); o[1] = f2b(a[1]); o[2] = f2b(a[2]); o[3] = f2b(a[3]);
    o[4] = f2b(b[0]); o[5] = f2b(b[1]); o[6] = f2b(b[2]); o[7] = f2b(b[3]);
    ((u16x8*)xb)[t] = o;
}

// -------- weight transpose+cvt: W[e][l][k][n] fp32 -> Bt[e*2+l][n][k 0..1023] bf16 -------
__global__ void transpose_kernel(const float* __restrict__ Wl, const float* __restrict__ Wr,
                                 u16* __restrict__ Bt) {
    int bid = blockIdx.x;
    int matid = bid >> 8;       // 0..15
    int tile = bid & 255;
    int em = matid >> 1;        // e*2+l
    int half = matid & 1;       // 0=Wl, 1=Wr
    const float* W = (half ? Wr : Wl) + (size_t)em * DD * DD;
    u16* out = Bt + (size_t)em * DD * 1024 + half * DD;
    int tk = (tile >> 4) * 32, tn = (tile & 15) * 32;
    __shared__ float s[32][33];
    int t = threadIdx.x;
    int rr = t >> 5, cc = t & 31;
#pragma unroll
    for (int p = 0; p < 4; ++p) {
        int kr = p * 8 + rr;
        s[kr][cc] = W[(size_t)(tk + kr) * DD + tn + cc];
    }
    __syncthreads();
#pragma unroll
    for (int p = 0; p < 4; ++p) {
        int nr = p * 8 + rr;
        out[(size_t)(tn + nr) * 1024 + tk + cc] = f2b(s[cc][nr]);
    }
}

// -------- gating (fp32 in): one wave per node -> w[i][4] (softmax val if top-2 else 0) ---
__global__ void gate_kernel(const float* __restrict__ x, const float* __restrict__ gw,
                            const float* __restrict__ gb, float* __restrict__ wg) {
    int node = blockIdx.x * 4 + (threadIdx.x >> 6);
    int l = threadIdx.x & 63;
    const f32x4* xr = (const f32x4*)(x + (size_t)node * DD) + l * 2;
    f32x4 x0 = xr[0], x1 = xr[1];
    float a0 = 0.f, a1 = 0.f, a2 = 0.f, a3 = 0.f;
#pragma unroll
    for (int j = 0; j < 8; ++j) {
        float xf = (j < 4) ? x0[j & 3] : x1[j & 3];
        f32x4 wr = ((const f32x4*)gw)[l * 8 + j];
        a0 += xf * wr[0]; a1 += xf * wr[1]; a2 += xf * wr[2]; a3 += xf * wr[3];
    }
#pragma unroll
    for (int off = 32; off > 0; off >>= 1) {
        a0 += __shfl_down(a0, off, 64);
        a1 += __shfl_down(a1, off, 64);
        a2 += __shfl_down(a2, off, 64);
        a3 += __shfl_down(a3, off, 64);
    }
    if (l == 0) {
        float lg[4] = {a0 + gb[0], a1 + gb[1], a2 + gb[2], a3 + gb[3]};
        float m = fmaxf(fmaxf(lg[0], lg[1]), fmaxf(lg[2], lg[3]));
        float p[4]; float s = 0.f;
#pragma unroll
        for (int e = 0; e < 4; ++e) { p[e] = expf(lg[e] - m); s += p[e]; }
        float inv = 1.f / s;
#pragma unroll
        for (int e = 0; e < 4; ++e) p[e] *= inv;
        int i0 = 0;
#pragma unroll
        for (int e = 1; e < 4; ++e) if (p[e] > p[i0]) i0 = e;
        int i1 = -1;
#pragma unroll
        for (int e = 0; e < 4; ++e) if (e != i0 && (i1 < 0 || p[e] > p[i1])) i1 = e;
        float o[4] = {0.f, 0.f, 0.f, 0.f};
        o[i0] = p[i0]; o[i1] = p[i1];
        float* w = wg + (size_t)node * 4;
        w[0] = o[0]; w[1] = o[1]; w[2] = o[2]; w[3] = o[3];
    }
}

// -------- CSR build ----------------------------------------------------------------------
__global__ void deg_kernel(const int* __restrict__ dst, int* __restrict__ deg) {
    int t = blockIdx.x * blockDim.x + threadIdx.x;
    if (t < EE) atomicAdd(&deg[dst[t]], 1);
}

__global__ void scan1_kernel(const int* __restrict__ deg, int* __restrict__ start,
                             float* __restrict__ invd, int* __restrict__ bsum) {
    int t = threadIdx.x;
    int idx = blockIdx.x * 1024 + t;
    int v = deg[idx];
    int sc = v;
#pragma unroll
    for (int off = 1; off < 64; off <<= 1) {
        int u = __shfl_up(sc, off, 64);
        if ((t & 63) >= off) sc += u;
    }
    __shared__ int wsum[16], woff[16];
    if ((t & 63) == 63) wsum[t >> 6] = sc;
    __syncthreads();
    if (t == 0) {
        int acc = 0;
        for (int w = 0; w < 16; ++w) { woff[w] = acc; acc += wsum[w]; }
        bsum[blockIdx.x] = acc;
    }
    __syncthreads();
    start[idx] = woff[t >> 6] + sc - v;   // local exclusive
    invd[idx] = v > 0 ? 1.0f / (float)v : 0.0f;
}

__global__ void scan2_kernel(int* __restrict__ bsum, int* __restrict__ boff) {
    if (threadIdx.x == 0) {
        int acc = 0;
        for (int b = 0; b < 32; ++b) { boff[b] = acc; acc += bsum[b]; }
    }
}

__global__ void scan3_kernel(int* __restrict__ start, int* __restrict__ cursor,
                             const int* __restrict__ boff) {
    int idx = blockIdx.x * 256 + threadIdx.x;
    int s = start[idx] + boff[idx >> 10];
    start[idx] = s;
    cursor[idx] = s;
}

__global__ void scatter_kernel(const int* __restrict__ src, const int* __restrict__ dst,
                               int* __restrict__ cursor, int* __restrict__ csr) {
    int t = blockIdx.x * blockDim.x + threadIdx.x;
    if (t < EE) {
        int d = dst[t];
        int pos = atomicAdd(&cursor[d], 1);
        csr[pos] = src[t];
    }
}

// -------- mean aggregation over CSR: one wave per node; F32IN: input fp32 else bf16 ------
template <bool F32IN>
__global__ void aggr_kernel(const void* __restrict__ hv, u16* __restrict__ out,
                            const int* __restrict__ start, const int* __restrict__ deg,
                            const int* __restrict__ csr, const float* __restrict__ invd,
                            const float* __restrict__ wg, int expert) {
    int node = blockIdx.x * 4 + (threadIdx.x >> 6);
    if (wg != nullptr && wg[(size_t)node * 4 + expert] == 0.f) return;  // unused row
    int l = threadIdx.x & 63;
    int s0 = start[node];
    int dg = deg[node];
    float a[8] = {0.f, 0.f, 0.f, 0.f, 0.f, 0.f, 0.f, 0.f};
    for (int p = 0; p < dg; ++p) {
        int j = csr[s0 + p];
        if (F32IN) {
            const f32x4* r = (const f32x4*)((const float*)hv + (size_t)j * DD) + l * 2;
            f32x4 v0 = r[0], v1 = r[1];
#pragma unroll
            for (int q = 0; q < 4; ++q) { a[q] += v0[q]; a[4 + q] += v1[q]; }
        } else {
            u16x8 v = *((const u16x8*)((const u16*)hv + (size_t)j * DD) + l);
#pragma unroll
            for (int q = 0; q < 8; ++q) a[q] += b2f(v[q]);
        }
    }
    float sc = invd[node];
    u16x8 o;
#pragma unroll
    for (int q = 0; q < 8; ++q) o[q] = f2b(a[q] * sc);
    *((u16x8*)(out + (size_t)node * DD) + l) = o;
}

// -------- fused GEMM: v = relu([A1|A2] @ Bt^T + bias) ------------------------------------
// A1: bf16 [M,512]. A2: bf16 (A2F32=false) or fp32 staged+cvt in LDS (A2F32=true).
// mode 0: Hout(bf16)       = v
// mode 1: Out(fp32, d_out) = wg[row][e] * v      (expert 0: unconditional, clears poison)
// mode 2: Out(fp32)       += wg[row][e] * v      (only where wg>0)
__device__ __forceinline__ void gload16(const void* g, void* l) {
    __builtin_amdgcn_global_load_lds((const __attribute__((address_space(1))) void*)g,
                                     (__attribute__((address_space(3))) void*)l, 16, 0, 0);
}

template <bool A2F32>
__global__ void __launch_bounds__(256) gemm_kernel(
    const u16* __restrict__ A1, const u16* __restrict__ A2b, const float* __restrict__ A2f,
    const u16* __restrict__ Bt, const float* __restrict__ bias,
    u16* __restrict__ Hout, float* __restrict__ Out,
    const float* __restrict__ wg, int expert, int mode) {
    __shared__ u16 lds[A2F32 ? 12288 : 8192];   // A (8/16 KB) + B (8 KB)
    u16* ldsA = lds;
    float* ldsF = (float*)lds;
    u16* ldsB = lds + (A2F32 ? 8192 : 4096);
    const int tid = threadIdx.x;
    const int lane = tid & 63;
    const int w = tid >> 6;
    const int bid = blockIdx.x;
    const int n0 = (bid & 3) * 128;
    const int m0 = (bid >> 2) * 128;
    const int wm = (w >> 1) * 64;
    const int wn = (w & 1) * 64;

    f32x4 acc[4][4];
#pragma unroll
    for (int i = 0; i < 4; ++i)
#pragma unroll
        for (int j = 0; j < 4; ++j) acc[i][j] = (f32x4){0.f, 0.f, 0.f, 0.f};

    // bf16 staging: phys 16B chunk p holds logical (row r, chunk c), c = (p&3) - (r>>1) mod 4
    const int p0 = tid, p1 = 256 + tid;
    const int r0 = p0 >> 2, c0 = ((p0 & 3) - (r0 >> 1)) & 3;
    const int r1 = p1 >> 2, c1 = ((p1 & 3) - (r1 >> 1)) & 3;
    const int arow = lane & 15;
    const int kc = lane >> 4;

    for (int kb = 0; kb < 32; ++kb) {
        __syncthreads();
        if (!A2F32 || kb < 16) {
            const u16* As = (kb < 16) ? A1 : A2b;
            const int kcol = (kb & 15) * 32;
            gload16(As + (size_t)(m0 + r0) * DD + kcol + c0 * 8, ldsA + p0 * 8);
            gload16(As + (size_t)(m0 + r1) * DD + kcol + c1 * 8, ldsA + p1 * 8);
        } else {
            // fp32 A tile: 128 rows x 32 floats; phys 16B chunk p = r*8 + ((c + r) & 7)
            const float* Af = A2f + (size_t)m0 * DD + (kb - 16) * 32;
#pragma unroll
            for (int q = 0; q < 4; ++q) {
                int p = q * 256 + tid;
                int rr = p >> 3, cpos = p & 7, cc2 = (cpos - rr) & 7;
                gload16(Af + (size_t)rr * DD + cc2 * 4, ldsF + p * 4);
            }
        }
        gload16(Bt + (size_t)(n0 + r0) * 1024 + kb * 32 + c0 * 8, ldsB + p0 * 8);
        gload16(Bt + (size_t)(n0 + r1) * 1024 + kb * 32 + c1 * 8, ldsB + p1 * 8);
        __syncthreads();
        s16x8 af[4], bf[4];
        if (!A2F32 || kb < 16) {
#pragma unroll
            for (int f = 0; f < 4; ++f) {
                int ra = wm + f * 16 + arow;
                int pa = (kc + (ra >> 1)) & 3;
                af[f] = *(const s16x8*)(ldsA + (ra * 4 + pa) * 8);
            }
        } else {
#pragma unroll
            for (int f = 0; f < 4; ++f) {
                int ra = wm + f * 16 + arow;
                int plo = ra * 8 + ((2 * kc + ra) & 7);
                int phi = ra * 8 + ((2 * kc + 1 + ra) & 7);
                f32x4 lo = *(const f32x4*)(ldsF + plo * 4);
                f32x4 hi = *(const f32x4*)(ldsF + phi * 4);
                s16x8 t;
                t[0] = (short)f2b(lo[0]); t[1] = (short)f2b(lo[1]);
                t[2] = (short)f2b(lo[2]); t[3] = (short)f2b(lo[3]);
                t[4] = (short)f2b(hi[0]); t[5] = (short)f2b(hi[1]);
                t[6] = (short)f2b(hi[2]); t[7] = (short)f2b(hi[3]);
                af[f] = t;
            }
        }
#pragma unroll
        for (int f = 0; f < 4; ++f) {
            int rb = wn + f * 16 + arow;
            int pb = (kc + (rb >> 1)) & 3;
            bf[f] = *(const s16x8*)(ldsB + (rb * 4 + pb) * 8);
        }
#pragma unroll
        for (int i = 0; i < 4; ++i)
#pragma unroll
            for (int j = 0; j < 4; ++j)
                acc[i][j] = __builtin_amdgcn_mfma_f32_16x16x32_bf16(af[i], bf[j], acc[i][j], 0, 0, 0);
    }

    const int colq = lane & 15;
    const int rq = lane >> 4;
#pragma unroll
    for (int i = 0; i < 4; ++i) {
#pragma unroll
        for (int j = 0; j < 4; ++j) {
            int col = n0 + wn + j * 16 + colq;
            float bv = bias[col];
#pragma unroll
            for (int r = 0; r < 4; ++r) {
                int row = m0 + wm + i * 16 + rq * 4 + r;
                float v = fmaxf(acc[i][j][r] + bv, 0.f);
                size_t idx = (size_t)row * DD + col;
                if (mode == 0) {
                    Hout[idx] = f2b(v);
                } else {
                    float wv = wg[(size_t)row * 4 + expert];
                    if (mode == 1) {
                        Out[idx] = wv * v;           // wv==0 -> exact 0 (clears poison)
                    } else if (wv > 0.f) {
                        Out[idx] += wv * v;
                    }
                }
            }
        }
    }
}

extern "C" void kernel_launch(void* const* d_in, const int* in_sizes, int n_in,
                              void* d_out, int out_size, void* d_ws, size_t ws_size,
                              hipStream_t stream) {
    const float* x  = (const float*)d_in[0];
    const float* gW = (const float*)d_in[1];
    const float* gb = (const float*)d_in[2];
    const float* Wl = (const float*)d_in[3];
    const float* bl = (const float*)d_in[4];
    const float* Wr = (const float*)d_in[5];
    const u32*   ei = (const u32*)d_in[6];
    float* outp = (float*)d_out;

    char* ws = (char*)d_ws;
    size_t off = 0;
    auto alloc = [&](size_t bytes) -> void* {
        void* p = ws + off;
        off += (bytes + 255) & ~(size_t)255;
        return p;
    };
    int*   flags  = (int*)alloc(512);                        // [0]=detect, +16 bsum, +64 boff
    float* wg     = (float*)alloc((size_t)NN * 4 * 4);
    int*   deg    = (int*)alloc((size_t)NN * 4);
    int*   start  = (int*)alloc((size_t)NN * 4);
    int*   cursor = (int*)alloc((size_t)NN * 4);
    float* invd   = (float*)alloc((size_t)NN * 4);
    int*   src32  = (int*)alloc((size_t)EE * 4);
    int*   dst32  = (int*)alloc((size_t)EE * 4);
    int*   csr    = (int*)alloc((size_t)EE * 4);
    u16*   Bt     = (u16*)alloc((size_t)8 * 512 * 1024 * 2); // 8 MB
    u16*   aggr0  = (u16*)alloc((size_t)NN * DD * 2);        // 32 MB
    u16*   h1     = (u16*)alloc((size_t)NN * DD * 2);        // 32 MB
    u16*   aggr1  = (u16*)alloc((size_t)NN * DD * 2);        // 32 MB
    size_t base_need = off;
    bool fast = ws_size >= base_need + (size_t)NN * DD * 2 + 256;
    u16* xb = fast ? (u16*)alloc((size_t)NN * DD * 2) : nullptr;  // 32 MB

    int* bsum = flags + 16;
    int* boff = flags + 64;

    hipMemsetAsync(deg, 0, (size_t)NN * 4, stream);

    detect_kernel<<<1, 64, 0, stream>>>(ei, flags);
    edges_kernel<<<EE / 256, 256, 0, stream>>>(ei, flags, src32, dst32);
    transpose_kernel<<<16 * 256, 256, 0, stream>>>(Wl, Wr, Bt);
    gate_kernel<<<NN / 4, 256, 0, stream>>>(x, gW, gb, wg);
    deg_kernel<<<EE / 256, 256, 0, stream>>>(dst32, deg);
    scan1_kernel<<<32, 1024, 0, stream>>>(deg, start, invd, bsum);
    scan2_kernel<<<1, 64, 0, stream>>>(bsum, boff);
    scan3_kernel<<<NN / 256, 256, 0, stream>>>(start, cursor, boff);
    scatter_kernel<<<EE / 256, 256, 0, stream>>>(src32, dst32, cursor, csr);

    if (fast) {
        convert_kernel<<<NN * DD / 8 / 256, 256, 0, stream>>>(x, xb);
        aggr_kernel<false><<<NN / 4, 256, 0, stream>>>(xb, aggr0, start, deg, csr, invd, nullptr, 0);
    } else {
        aggr_kernel<true><<<NN / 4, 256, 0, stream>>>(x, aggr0, start, deg, csr, invd, nullptr, 0);
    }

    for (int e = 0; e < 4; ++e) {
        const u16* BtL0 = Bt + (size_t)(e * 2 + 0) * 512 * 1024;
        const u16* BtL1 = Bt + (size_t)(e * 2 + 1) * 512 * 1024;
        const float* b0 = bl + (e * 2 + 0) * 512;
        const float* b1 = bl + (e * 2 + 1) * 512;
        // layer 0: h1 = relu(aggr0 @ Wl[e,0] + bl[e,0] + x @ Wr[e,0])   (dense)
        if (fast)
            gemm_kernel<false><<<1024, 256, 0, stream>>>(aggr0, xb, nullptr, BtL0, b0,
                                                         h1, nullptr, nullptr, e, 0);
        else
            gemm_kernel<true><<<1024, 256, 0, stream>>>(aggr0, nullptr, x, BtL0, b0,
                                                        h1, nullptr, nullptr, e, 0);
        // layer 1 aggregation (only rows that selected expert e)
        aggr_kernel<false><<<NN / 4, 256, 0, stream>>>(h1, aggr1, start, deg, csr, invd, wg, e);
        // layer 1: out (+)= w[i][e] * relu(aggr1 @ Wl[e,1] + bl[e,1] + h1 @ Wr[e,1])
        gemm_kernel<false><<<1024, 256, 0, stream>>>(aggr1, h1, nullptr, BtL1, b1,
                                                     nullptr, outp, wg, e, (e == 0) ? 1 : 2);
    }
}

// Round 6
// 1122.797 us; speedup vs baseline: 1.0049x; 1.0049x over previous
//
#include <hip/hip_runtime.h>

typedef unsigned short u16;
typedef unsigned int u32;
typedef u16 u16x8 __attribute__((ext_vector_type(8)));
typedef short s16x8 __attribute__((ext_vector_type(8)));
typedef float f32x4 __attribute__((ext_vector_type(4)));

#define NN 32768
#define EE 262144
#define DD 512
#define WMAT (512 * 1024)   // elements per Bt matrix

__device__ __forceinline__ float b2f(u16 u) {
    return __uint_as_float(((u32)u) << 16);
}
__device__ __forceinline__ u16 f2b(float f) {
    u32 u = __float_as_uint(f);
    u32 r = (u + 0x7FFFu + ((u >> 16) & 1u)) >> 16;
    return (u16)r;
}

// -------- edge-index width detection: int64 (high words zero) vs int32 ------------------
__global__ void detect_kernel(const u32* __restrict__ ei, int* __restrict__ flags) {
    if (threadIdx.x == 0) {
        int allzero = 1;
        for (int i = 0; i < 64; ++i)
            if (ei[2 * i + 1] != 0u) allzero = 0;
        flags[0] = allzero;  // 1 => int64 layout
    }
}

__global__ void edges_kernel(const u32* __restrict__ ei, const int* __restrict__ flags,
                             int* __restrict__ s32, int* __restrict__ d32) {
    int t = blockIdx.x * 256 + threadIdx.x;
    u32 s, d;
    if (flags[0]) {  // int64
        s = ei[2 * t];
        d = ei[2 * EE + 2 * t];
    } else {         // int32
        s = ei[t];
        d = ei[EE + t];
    }
    s32[t] = (int)(s & (NN - 1));
    d32[t] = (int)(d & (NN - 1));
}

// -------- fp32 x -> bf16 xb --------------------------------------------------------------
__global__ void convert_kernel(const float* __restrict__ x, u16* __restrict__ xb) {
    int t = blockIdx.x * 256 + threadIdx.x;
    f32x4 a = ((const f32x4*)x)[t * 2];
    f32x4 b = ((const f32x4*)x)[t * 2 + 1];
    u16x8 o;
    o[0] = f2b(a[0]); o[1] = f2b(a[1]); o[2] = f2b(a[2]); o[3] = f2b(a[3]);
    o[4] = f2b(b[0]); o[5] = f2b(b[1]); o[6] = f2b(b[2]); o[7] = f2b(b[3]);
    ((u16x8*)xb)[t] = o;
}

// -------- weight transpose+cvt: W[e][l][k][n] fp32 -> Bt[e*2+l][n][k 0..1023] bf16 -------
__global__ void transpose_kernel(const float* __restrict__ Wl, const float* __restrict__ Wr,
                                 u16* __restrict__ Bt) {
    int bid = blockIdx.x;
    int matid = bid >> 8;
    int tile = bid & 255;
    int em = matid >> 1;
    int half = matid & 1;
    const float* W = (half ? Wr : Wl) + (size_t)em * DD * DD;
    u16* out = Bt + (size_t)em * DD * 1024 + half * DD;
    int tk = (tile >> 4) * 32, tn = (tile & 15) * 32;
    __shared__ float s[32][33];
    int t = threadIdx.x;
    int rr = t >> 5, cc = t & 31;
#pragma unroll
    for (int p = 0; p < 4; ++p) {
        int kr = p * 8 + rr;
        s[kr][cc] = W[(size_t)(tk + kr) * DD + tn + cc];
    }
    __syncthreads();
#pragma unroll
    for (int p = 0; p < 4; ++p) {
        int nr = p * 8 + rr;
        out[(size_t)(tn + nr) * 1024 + tk + cc] = f2b(s[cc][nr]);
    }
}

// -------- gating -------------------------------------------------------------------------
__global__ void gate_kernel(const float* __restrict__ x, const float* __restrict__ gw,
                            const float* __restrict__ gb, float* __restrict__ wg) {
    int node = blockIdx.x * 4 + (threadIdx.x >> 6);
    int l = threadIdx.x & 63;
    const f32x4* xr = (const f32x4*)(x + (size_t)node * DD) + l * 2;
    f32x4 x0 = xr[0], x1 = xr[1];
    float a0 = 0.f, a1 = 0.f, a2 = 0.f, a3 = 0.f;
#pragma unroll
    for (int j = 0; j < 8; ++j) {
        float xf = (j < 4) ? x0[j & 3] : x1[j & 3];
        f32x4 wr = ((const f32x4*)gw)[l * 8 + j];
        a0 += xf * wr[0]; a1 += xf * wr[1]; a2 += xf * wr[2]; a3 += xf * wr[3];
    }
#pragma unroll
    for (int off = 32; off > 0; off >>= 1) {
        a0 += __shfl_down(a0, off, 64);
        a1 += __shfl_down(a1, off, 64);
        a2 += __shfl_down(a2, off, 64);
        a3 += __shfl_down(a3, off, 64);
    }
    if (l == 0) {
        float lg[4] = {a0 + gb[0], a1 + gb[1], a2 + gb[2], a3 + gb[3]};
        float m = fmaxf(fmaxf(lg[0], lg[1]), fmaxf(lg[2], lg[3]));
        float p[4]; float s = 0.f;
#pragma unroll
        for (int e = 0; e < 4; ++e) { p[e] = expf(lg[e] - m); s += p[e]; }
        float inv = 1.f / s;
#pragma unroll
        for (int e = 0; e < 4; ++e) p[e] *= inv;
        int i0 = 0;
#pragma unroll
        for (int e = 1; e < 4; ++e) if (p[e] > p[i0]) i0 = e;
        int i1 = -1;
#pragma unroll
        for (int e = 0; e < 4; ++e) if (e != i0 && (i1 < 0 || p[e] > p[i1])) i1 = e;
        float o[4] = {0.f, 0.f, 0.f, 0.f};
        o[i0] = p[i0]; o[i1] = p[i1];
        float* w = wg + (size_t)node * 4;
        w[0] = o[0]; w[1] = o[1]; w[2] = o[2]; w[3] = o[3];
    }
}

// -------- CSR build ----------------------------------------------------------------------
__global__ void deg_kernel(const int* __restrict__ dst, int* __restrict__ deg) {
    int t = blockIdx.x * blockDim.x + threadIdx.x;
    if (t < EE) atomicAdd(&deg[dst[t]], 1);
}

__global__ void scan1_kernel(const int* __restrict__ deg, int* __restrict__ start,
                             float* __restrict__ invd, int* __restrict__ bsum) {
    int t = threadIdx.x;
    int idx = blockIdx.x * 1024 + t;
    int v = deg[idx];
    int sc = v;
#pragma unroll
    for (int off = 1; off < 64; off <<= 1) {
        int u = __shfl_up(sc, off, 64);
        if ((t & 63) >= off) sc += u;
    }
    __shared__ int wsum[16], woff[16];
    if ((t & 63) == 63) wsum[t >> 6] = sc;
    __syncthreads();
    if (t == 0) {
        int acc = 0;
        for (int w = 0; w < 16; ++w) { woff[w] = acc; acc += wsum[w]; }
        bsum[blockIdx.x] = acc;
    }
    __syncthreads();
    start[idx] = woff[t >> 6] + sc - v;
    invd[idx] = v > 0 ? 1.0f / (float)v : 0.0f;
}

__global__ void scan2_kernel(int* __restrict__ bsum, int* __restrict__ boff) {
    if (threadIdx.x == 0) {
        int acc = 0;
        for (int b = 0; b < 32; ++b) { boff[b] = acc; acc += bsum[b]; }
    }
}

__global__ void scan3_kernel(int* __restrict__ start, int* __restrict__ cursor,
                             const int* __restrict__ boff) {
    int idx = blockIdx.x * 256 + threadIdx.x;
    int s = start[idx] + boff[idx >> 10];
    start[idx] = s;
    cursor[idx] = s;
}

__global__ void scatter_kernel(const int* __restrict__ src, const int* __restrict__ dst,
                               int* __restrict__ cursor, int* __restrict__ csr) {
    int t = blockIdx.x * blockDim.x + threadIdx.x;
    if (t < EE) {
        int d = dst[t];
        int pos = atomicAdd(&cursor[d], 1);
        csr[pos] = src[t];
    }
}

// -------- mean aggregation over CSR ------------------------------------------------------
template <bool F32IN>
__global__ void aggr_kernel(const void* __restrict__ hv, u16* __restrict__ out,
                            const int* __restrict__ start, const int* __restrict__ deg,
                            const int* __restrict__ csr, const float* __restrict__ invd,
                            const float* __restrict__ wg, int expert) {
    int node = blockIdx.x * 4 + (threadIdx.x >> 6);
    if (wg != nullptr && wg[(size_t)node * 4 + expert] == 0.f) return;
    int l = threadIdx.x & 63;
    int s0 = start[node];
    int dg = deg[node];
    float a[8] = {0.f, 0.f, 0.f, 0.f, 0.f, 0.f, 0.f, 0.f};
    for (int p = 0; p < dg; ++p) {
        int j = csr[s0 + p];
        if (F32IN) {
            const f32x4* r = (const f32x4*)((const float*)hv + (size_t)j * DD) + l * 2;
            f32x4 v0 = r[0], v1 = r[1];
#pragma unroll
            for (int q = 0; q < 4; ++q) { a[q] += v0[q]; a[4 + q] += v1[q]; }
        } else {
            u16x8 v = *((const u16x8*)((const u16*)hv + (size_t)j * DD) + l);
#pragma unroll
            for (int q = 0; q < 8; ++q) a[q] += b2f(v[q]);
        }
    }
    float sc = invd[node];
    u16x8 o;
#pragma unroll
    for (int q = 0; q < 8; ++q) o[q] = f2b(a[q] * sc);
    *((u16x8*)(out + (size_t)node * DD) + l) = o;
}

__device__ __forceinline__ void gload16(const void* g, void* l) {
    __builtin_amdgcn_global_load_lds((const __attribute__((address_space(1))) void*)g,
                                     (__attribute__((address_space(3))) void*)l, 16, 0, 0);
}

// -------- fused GEMM: v = relu([A1_e|A2_e] @ Bt_e^T + bias_e) ----------------------------
// Decode: xcd=bid&7, local=bid>>3; m-tile = xcd*32 + local/ntt (XCD-local A reuse),
// sub = local%ntt: expert = sub>>2 (pointer strides), n-tile = sub&3.
// GATING expert: eParam if >=0 (single-expert launches where strides are 0), else decoded.
// mode 0: Hout_e(bf16) = v;  mode 1: Out = wv*v;  mode 2: Out += wv*v (wv>0). No atomics.
template <bool A2F32>
__global__ void __launch_bounds__(256) gemm_kernel(
    const u16* __restrict__ A1, const u16* __restrict__ A2b, const float* __restrict__ A2f,
    size_t sA, const u16* __restrict__ Bt, size_t sBt,
    const float* __restrict__ bias, size_t sBias,
    u16* __restrict__ Hout, size_t sH, float* __restrict__ Out,
    const float* __restrict__ wg, int mode, int eParam, int ntt) {
    __shared__ u16 lds[A2F32 ? 12288 : 8192];
    u16* ldsA = lds;
    float* ldsF = (float*)lds;
    u16* ldsB = lds + (A2F32 ? 8192 : 4096);
    const int tid = threadIdx.x;
    const int lane = tid & 63;
    const int w = tid >> 6;

    const int bid = blockIdx.x;
    const int xcd = bid & 7;
    const int local = bid >> 3;
    const int mtl = local / ntt;
    const int sub = local - mtl * ntt;
    const int expert = sub >> 2;            // pointer-stride expert (0 when ntt==4)
    const int wgE = (eParam >= 0) ? eParam : expert;   // gating expert (the r4/r5 bug fix)
    const int m0 = (xcd * 32 + mtl) * 128;
    const int n0 = (sub & 3) * 128;

    const u16* A1p = A1 + (size_t)expert * sA;
    const u16* A2p = A2b + (size_t)expert * sA;
    const u16* Btp = Bt + (size_t)expert * sBt;
    const float* biasp = bias + (size_t)expert * sBias;
    u16* Houtp = Hout + (size_t)expert * sH;

    const int wm = (w >> 1) * 64;
    const int wn = (w & 1) * 64;

    f32x4 acc[4][4];
#pragma unroll
    for (int i = 0; i < 4; ++i)
#pragma unroll
        for (int j = 0; j < 4; ++j) acc[i][j] = (f32x4){0.f, 0.f, 0.f, 0.f};

    const int p0 = tid, p1 = 256 + tid;
    const int r0 = p0 >> 2, c0 = ((p0 & 3) - (r0 >> 1)) & 3;
    const int r1 = p1 >> 2, c1 = ((p1 & 3) - (r1 >> 1)) & 3;
    const int arow = lane & 15;
    const int kc = lane >> 4;

    for (int kb = 0; kb < 32; ++kb) {
        __syncthreads();
        if (!A2F32 || kb < 16) {
            const u16* As = (kb < 16) ? A1p : A2p;
            const int kcol = (kb & 15) * 32;
            gload16(As + (size_t)(m0 + r0) * DD + kcol + c0 * 8, ldsA + p0 * 8);
            gload16(As + (size_t)(m0 + r1) * DD + kcol + c1 * 8, ldsA + p1 * 8);
        } else {
            const float* Af = A2f + (size_t)m0 * DD + (kb - 16) * 32;
#pragma unroll
            for (int q = 0; q < 4; ++q) {
                int p = q * 256 + tid;
                int rr = p >> 3, cpos = p & 7, cc2 = (cpos - rr) & 7;
                gload16(Af + (size_t)rr * DD + cc2 * 4, ldsF + p * 4);
            }
        }
        gload16(Btp + (size_t)(n0 + r0) * 1024 + kb * 32 + c0 * 8, ldsB + p0 * 8);
        gload16(Btp + (size_t)(n0 + r1) * 1024 + kb * 32 + c1 * 8, ldsB + p1 * 8);
        __syncthreads();
        s16x8 af[4], bf[4];
        if (!A2F32 || kb < 16) {
#pragma unroll
            for (int f = 0; f < 4; ++f) {
                int ra = wm + f * 16 + arow;
                int pa = (kc + (ra >> 1)) & 3;
                af[f] = *(const s16x8*)(ldsA + (ra * 4 + pa) * 8);
            }
        } else {
#pragma unroll
            for (int f = 0; f < 4; ++f) {
                int ra = wm + f * 16 + arow;
                int plo = ra * 8 + ((2 * kc + ra) & 7);
                int phi = ra * 8 + ((2 * kc + 1 + ra) & 7);
                f32x4 lo = *(const f32x4*)(ldsF + plo * 4);
                f32x4 hi = *(const f32x4*)(ldsF + phi * 4);
                s16x8 t;
                t[0] = (short)f2b(lo[0]); t[1] = (short)f2b(lo[1]);
                t[2] = (short)f2b(lo[2]); t[3] = (short)f2b(lo[3]);
                t[4] = (short)f2b(hi[0]); t[5] = (short)f2b(hi[1]);
                t[6] = (short)f2b(hi[2]); t[7] = (short)f2b(hi[3]);
                af[f] = t;
            }
        }
#pragma unroll
        for (int f = 0; f < 4; ++f) {
            int rb = wn + f * 16 + arow;
            int pb = (kc + (rb >> 1)) & 3;
            bf[f] = *(const s16x8*)(ldsB + (rb * 4 + pb) * 8);
        }
#pragma unroll
        for (int i = 0; i < 4; ++i)
#pragma unroll
            for (int j = 0; j < 4; ++j)
                acc[i][j] = __builtin_amdgcn_mfma_f32_16x16x32_bf16(af[i], bf[j], acc[i][j], 0, 0, 0);
    }

    const int colq = lane & 15;
    const int rq = lane >> 4;
#pragma unroll
    for (int i = 0; i < 4; ++i) {
#pragma unroll
        for (int j = 0; j < 4; ++j) {
            int col = n0 + wn + j * 16 + colq;
            float bv = biasp[col];
#pragma unroll
            for (int r = 0; r < 4; ++r) {
                int row = m0 + wm + i * 16 + rq * 4 + r;
                float v = fmaxf(acc[i][j][r] + bv, 0.f);
                size_t idx = (size_t)row * DD + col;
                if (mode == 0) {
                    Houtp[idx] = f2b(v);
                } else {
                    float wv = wg[(size_t)row * 4 + wgE];
                    if (mode == 1) {
                        Out[idx] = wv * v;
                    } else {
                        if (wv > 0.f) Out[idx] += wv * v;
                    }
                }
            }
        }
    }
}

extern "C" void kernel_launch(void* const* d_in, const int* in_sizes, int n_in,
                              void* d_out, int out_size, void* d_ws, size_t ws_size,
                              hipStream_t stream) {
    const float* x  = (const float*)d_in[0];
    const float* gW = (const float*)d_in[1];
    const float* gb = (const float*)d_in[2];
    const float* Wl = (const float*)d_in[3];
    const float* bl = (const float*)d_in[4];
    const float* Wr = (const float*)d_in[5];
    const u32*   ei = (const u32*)d_in[6];
    float* outp = (float*)d_out;

    char* ws = (char*)d_ws;
    size_t off = 0;
    auto alloc = [&](size_t bytes) -> void* {
        void* p = ws + off;
        off += (bytes + 255) & ~(size_t)255;
        return p;
    };
    const size_t MB32 = (size_t)NN * DD * 2;
    int*   flags  = (int*)alloc(512);
    float* wg     = (float*)alloc((size_t)NN * 4 * 4);
    int*   deg    = (int*)alloc((size_t)NN * 4);
    int*   start  = (int*)alloc((size_t)NN * 4);
    int*   cursor = (int*)alloc((size_t)NN * 4);
    float* invd   = (float*)alloc((size_t)NN * 4);
    int*   src32  = (int*)alloc((size_t)EE * 4);
    int*   dst32  = (int*)alloc((size_t)EE * 4);
    int*   csr    = (int*)alloc((size_t)EE * 4);
    u16*   Bt     = (u16*)alloc((size_t)8 * WMAT * 2);       // 8 MB
    u16*   aggr0  = (u16*)alloc(MB32);                       // 32 MB

    size_t rem = (ws_size > off) ? ws_size - off : 0;
    // tier 1 (B): h1[4] (128 MB), aggr1 aliases aggr0 (dead after fused L0) -> ~173 MB total
    // tier 2 (C-fast): xb + h1 + aggr1 (96 MB) -> ~141 MB total (round-3 proven)
    // tier 3 (C-slow): h1 + aggr1 (64 MB) -> ~109 MB total (round-3 proven fallback)
    int tier;
    if      (rem >= 4 * MB32 + 65536) tier = 1;
    else if (rem >= 3 * MB32 + 65536) tier = 2;
    else                              tier = 3;

    u16 *xb = nullptr, *h1 = nullptr, *aggr1 = nullptr;
    if (tier == 1) {
        h1 = (u16*)alloc(4 * MB32);
        aggr1 = aggr0;                      // safe: aggr0 dead after fused layer-0
    } else if (tier == 2) {
        xb = (u16*)alloc(MB32);
        h1 = (u16*)alloc(MB32);
        aggr1 = (u16*)alloc(MB32);
    } else {
        h1 = (u16*)alloc(MB32);
        aggr1 = (u16*)alloc(MB32);
    }

    int* bsum = flags + 16;
    int* boff = flags + 64;

    hipMemsetAsync(deg, 0, (size_t)NN * 4, stream);

    detect_kernel<<<1, 64, 0, stream>>>(ei, flags);
    edges_kernel<<<EE / 256, 256, 0, stream>>>(ei, flags, src32, dst32);
    transpose_kernel<<<16 * 256, 256, 0, stream>>>(Wl, Wr, Bt);
    gate_kernel<<<NN / 4, 256, 0, stream>>>(x, gW, gb, wg);
    deg_kernel<<<EE / 256, 256, 0, stream>>>(dst32, deg);
    scan1_kernel<<<32, 1024, 0, stream>>>(deg, start, invd, bsum);
    scan2_kernel<<<1, 64, 0, stream>>>(bsum, boff);
    scan3_kernel<<<NN / 256, 256, 0, stream>>>(start, cursor, boff);
    scatter_kernel<<<EE / 256, 256, 0, stream>>>(src32, dst32, cursor, csr);

    if (tier == 1) {
        // layer-0 aggregation straight from fp32 x (no xb needed)
        aggr_kernel<true><<<NN / 4, 256, 0, stream>>>(x, aggr0, start, deg, csr, invd, nullptr, 0);
        // fused layer 0 across all 4 experts: A ([aggr0|x]) read once, per-expert B/bias/h1
        gemm_kernel<true><<<256 * 16, 256, 0, stream>>>(
            aggr0, nullptr, x, /*sA=*/0, Bt, /*sBt=*/2 * WMAT, bl, /*sBias=*/1024,
            h1, /*sH=*/(size_t)NN * DD, nullptr, wg, /*mode=*/0, /*eParam=*/-1, /*ntt=*/16);
        // sequential layer 1 (proven epilogue, correct per-expert gating via eParam)
        for (int e = 0; e < 4; ++e) {
            aggr_kernel<false><<<NN / 4, 256, 0, stream>>>(
                h1 + (size_t)e * NN * DD, aggr1, start, deg, csr, invd, wg, e);
            gemm_kernel<false><<<256 * 4, 256, 0, stream>>>(
                aggr1, h1 + (size_t)e * NN * DD, nullptr, 0,
                Bt + (size_t)(e * 2 + 1) * WMAT, 0, bl + (e * 2 + 1) * 512, 0,
                nullptr, 0, outp, wg, (e == 0) ? 1 : 2, /*eParam=*/e, /*ntt=*/4);
        }
    } else {
        if (tier == 2) {
            convert_kernel<<<NN * DD / 8 / 256, 256, 0, stream>>>(x, xb);
            aggr_kernel<false><<<NN / 4, 256, 0, stream>>>(xb, aggr0, start, deg, csr, invd,
                                                           nullptr, 0);
        } else {
            aggr_kernel<true><<<NN / 4, 256, 0, stream>>>(x, aggr0, start, deg, csr, invd,
                                                          nullptr, 0);
        }
        for (int e = 0; e < 4; ++e) {
            const u16* BtL0 = Bt + (size_t)(e * 2 + 0) * WMAT;
            const u16* BtL1 = Bt + (size_t)(e * 2 + 1) * WMAT;
            const float* b0 = bl + (e * 2 + 0) * 512;
            const float* b1 = bl + (e * 2 + 1) * 512;
            if (tier == 2)
                gemm_kernel<false><<<256 * 4, 256, 0, stream>>>(
                    aggr0, xb, nullptr, 0, BtL0, 0, b0, 0, h1, 0, nullptr, wg, 0, e, 4);
            else
                gemm_kernel<true><<<256 * 4, 256, 0, stream>>>(
                    aggr0, nullptr, x, 0, BtL0, 0, b0, 0, h1, 0, nullptr, wg, 0, e, 4);
            aggr_kernel<false><<<NN / 4, 256, 0, stream>>>(h1, aggr1, start, deg, csr, invd, wg, e);
            gemm_kernel<false><<<256 * 4, 256, 0, stream>>>(
                aggr1, h1, nullptr, 0, BtL1, 0, b1, 0, nullptr, 0, outp, wg,
                (e == 0) ? 1 : 2, e, 4);
        }
    }
}

// Round 7
// 939.786 us; speedup vs baseline: 1.2005x; 1.1947x over previous
//
#include <hip/hip_runtime.h>

typedef unsigned short u16;
typedef unsigned int u32;
typedef u16 u16x8 __attribute__((ext_vector_type(8)));
typedef short s16x8 __attribute__((ext_vector_type(8)));
typedef float f32x4 __attribute__((ext_vector_type(4)));

#define NN 32768
#define EE 262144
#define DD 512
#define WMAT (512 * 1024)   // elements per Bt matrix

__device__ __forceinline__ float b2f(u16 u) {
    return __uint_as_float(((u32)u) << 16);
}
__device__ __forceinline__ u16 f2b(float f) {
    u32 u = __float_as_uint(f);
    u32 r = (u + 0x7FFFu + ((u >> 16) & 1u)) >> 16;
    return (u16)r;
}

// -------- edge-index width detection: int64 (high words zero) vs int32 ------------------
__global__ void detect_kernel(const u32* __restrict__ ei, int* __restrict__ flags) {
    if (threadIdx.x == 0) {
        int allzero = 1;
        for (int i = 0; i < 64; ++i)
            if (ei[2 * i + 1] != 0u) allzero = 0;
        flags[0] = allzero;  // 1 => int64 layout
    }
}

__global__ void edges_kernel(const u32* __restrict__ ei, const int* __restrict__ flags,
                             int* __restrict__ s32, int* __restrict__ d32) {
    int t = blockIdx.x * 256 + threadIdx.x;
    u32 s, d;
    if (flags[0]) {  // int64
        s = ei[2 * t];
        d = ei[2 * EE + 2 * t];
    } else {         // int32
        s = ei[t];
        d = ei[EE + t];
    }
    s32[t] = (int)(s & (NN - 1));
    d32[t] = (int)(d & (NN - 1));
}

// -------- fp32 x -> bf16 xb --------------------------------------------------------------
__global__ void convert_kernel(const float* __restrict__ x, u16* __restrict__ xb) {
    int t = blockIdx.x * 256 + threadIdx.x;
    f32x4 a = ((const f32x4*)x)[t * 2];
    f32x4 b = ((const f32x4*)x)[t * 2 + 1];
    u16x8 o;
    o[0] = f2b(a[0]); o[1] = f2b(a[1]); o[2] = f2b(a[2]); o[3] = f2b(a[3]);
    o[4] = f2b(b[0]); o[5] = f2b(b[1]); o[6] = f2b(b[2]); o[7] = f2b(b[3]);
    ((u16x8*)xb)[t] = o;
}

// -------- weight transpose+cvt: W[e][l][k][n] fp32 -> Bt[e*2+l][n][k 0..1023] bf16 -------
__global__ void transpose_kernel(const float* __restrict__ Wl, const float* __restrict__ Wr,
                                 u16* __restrict__ Bt) {
    int bid = blockIdx.x;
    int matid = bid >> 8;
    int tile = bid & 255;
    int em = matid >> 1;
    int half = matid & 1;
    const float* W = (half ? Wr : Wl) + (size_t)em * DD * DD;
    u16* out = Bt + (size_t)em * DD * 1024 + half * DD;
    int tk = (tile >> 4) * 32, tn = (tile & 15) * 32;
    __shared__ float s[32][33];
    int t = threadIdx.x;
    int rr = t >> 5, cc = t & 31;
#pragma unroll
    for (int p = 0; p < 4; ++p) {
        int kr = p * 8 + rr;
        s[kr][cc] = W[(size_t)(tk + kr) * DD + tn + cc];
    }
    __syncthreads();
#pragma unroll
    for (int p = 0; p < 4; ++p) {
        int nr = p * 8 + rr;
        out[(size_t)(tn + nr) * 1024 + tk + cc] = f2b(s[cc][nr]);
    }
}

// -------- gating -------------------------------------------------------------------------
__global__ void gate_kernel(const float* __restrict__ x, const float* __restrict__ gw,
                            const float* __restrict__ gb, float* __restrict__ wg) {
    int node = blockIdx.x * 4 + (threadIdx.x >> 6);
    int l = threadIdx.x & 63;
    const f32x4* xr = (const f32x4*)(x + (size_t)node * DD) + l * 2;
    f32x4 x0 = xr[0], x1 = xr[1];
    float a0 = 0.f, a1 = 0.f, a2 = 0.f, a3 = 0.f;
#pragma unroll
    for (int j = 0; j < 8; ++j) {
        float xf = (j < 4) ? x0[j & 3] : x1[j & 3];
        f32x4 wr = ((const f32x4*)gw)[l * 8 + j];
        a0 += xf * wr[0]; a1 += xf * wr[1]; a2 += xf * wr[2]; a3 += xf * wr[3];
    }
#pragma unroll
    for (int off = 32; off > 0; off >>= 1) {
        a0 += __shfl_down(a0, off, 64);
        a1 += __shfl_down(a1, off, 64);
        a2 += __shfl_down(a2, off, 64);
        a3 += __shfl_down(a3, off, 64);
    }
    if (l == 0) {
        float lg[4] = {a0 + gb[0], a1 + gb[1], a2 + gb[2], a3 + gb[3]};
        float m = fmaxf(fmaxf(lg[0], lg[1]), fmaxf(lg[2], lg[3]));
        float p[4]; float s = 0.f;
#pragma unroll
        for (int e = 0; e < 4; ++e) { p[e] = expf(lg[e] - m); s += p[e]; }
        float inv = 1.f / s;
#pragma unroll
        for (int e = 0; e < 4; ++e) p[e] *= inv;
        int i0 = 0;
#pragma unroll
        for (int e = 1; e < 4; ++e) if (p[e] > p[i0]) i0 = e;
        int i1 = -1;
#pragma unroll
        for (int e = 0; e < 4; ++e) if (e != i0 && (i1 < 0 || p[e] > p[i1])) i1 = e;
        float o[4] = {0.f, 0.f, 0.f, 0.f};
        o[i0] = p[i0]; o[i1] = p[i1];
        float* w = wg + (size_t)node * 4;
        w[0] = o[0]; w[1] = o[1]; w[2] = o[2]; w[3] = o[3];
    }
}

// -------- CSR build ----------------------------------------------------------------------
__global__ void deg_kernel(const int* __restrict__ dst, int* __restrict__ deg) {
    int t = blockIdx.x * blockDim.x + threadIdx.x;
    if (t < EE) atomicAdd(&deg[dst[t]], 1);
}

__global__ void scan1_kernel(const int* __restrict__ deg, int* __restrict__ start,
                             float* __restrict__ invd, int* __restrict__ bsum) {
    int t = threadIdx.x;
    int idx = blockIdx.x * 1024 + t;
    int v = deg[idx];
    int sc = v;
#pragma unroll
    for (int off = 1; off < 64; off <<= 1) {
        int u = __shfl_up(sc, off, 64);
        if ((t & 63) >= off) sc += u;
    }
    __shared__ int wsum[16], woff[16];
    if ((t & 63) == 63) wsum[t >> 6] = sc;
    __syncthreads();
    if (t == 0) {
        int acc = 0;
        for (int w = 0; w < 16; ++w) { woff[w] = acc; acc += wsum[w]; }
        bsum[blockIdx.x] = acc;
    }
    __syncthreads();
    start[idx] = woff[t >> 6] + sc - v;
    invd[idx] = v > 0 ? 1.0f / (float)v : 0.0f;
}

__global__ void scan2_kernel(int* __restrict__ bsum, int* __restrict__ boff) {
    if (threadIdx.x == 0) {
        int acc = 0;
        for (int b = 0; b < 32; ++b) { boff[b] = acc; acc += bsum[b]; }
    }
}

__global__ void scan3_kernel(int* __restrict__ start, int* __restrict__ cursor,
                             const int* __restrict__ boff) {
    int idx = blockIdx.x * 256 + threadIdx.x;
    int s = start[idx] + boff[idx >> 10];
    start[idx] = s;
    cursor[idx] = s;
}

__global__ void scatter_kernel(const int* __restrict__ src, const int* __restrict__ dst,
                               int* __restrict__ cursor, int* __restrict__ csr) {
    int t = blockIdx.x * blockDim.x + threadIdx.x;
    if (t < EE) {
        int d = dst[t];
        int pos = atomicAdd(&cursor[d], 1);
        csr[pos] = src[t];
    }
}

// -------- mean aggregation over CSR; multi-expert: grid = nExp*8192 blocks ---------------
// expert = eBase + bid>>13; input/output advance by `stride` elements per expert slot.
template <bool F32IN>
__global__ void aggr_kernel(const void* __restrict__ hv, u16* __restrict__ outB,
                            const int* __restrict__ start, const int* __restrict__ deg,
                            const int* __restrict__ csr, const float* __restrict__ invd,
                            const float* __restrict__ wg, int eBase, size_t stride) {
    int eo = blockIdx.x >> 13;
    int node = ((blockIdx.x & 8191) << 2) + (threadIdx.x >> 6);
    int expert = eBase + eo;
    if (wg != nullptr && wg[(size_t)node * 4 + expert] == 0.f) return;
    int l = threadIdx.x & 63;
    int s0 = start[node];
    int dg = deg[node];
    u16* out = outB + (size_t)eo * stride;
    float a[8] = {0.f, 0.f, 0.f, 0.f, 0.f, 0.f, 0.f, 0.f};
    for (int p = 0; p < dg; ++p) {
        int j = csr[s0 + p];
        if (F32IN) {
            const float* h = (const float*)hv + (size_t)eo * stride;
            const f32x4* r = (const f32x4*)(h + (size_t)j * DD) + l * 2;
            f32x4 v0 = r[0], v1 = r[1];
#pragma unroll
            for (int q = 0; q < 4; ++q) { a[q] += v0[q]; a[4 + q] += v1[q]; }
        } else {
            const u16* h = (const u16*)hv + (size_t)eo * stride;
            u16x8 v = *((const u16x8*)(h + (size_t)j * DD) + l);
#pragma unroll
            for (int q = 0; q < 8; ++q) a[q] += b2f(v[q]);
        }
    }
    float sc = invd[node];
    u16x8 o;
#pragma unroll
    for (int q = 0; q < 8; ++q) o[q] = f2b(a[q] * sc);
    *((u16x8*)(out + (size_t)node * DD) + l) = o;
}

__device__ __forceinline__ void gload16(const void* g, void* l) {
    __builtin_amdgcn_global_load_lds((const __attribute__((address_space(1))) void*)g,
                                     (__attribute__((address_space(3))) void*)l, 16, 0, 0);
}

// -------- fused GEMM: v = relu([A1_e|A2_e] @ Bt_e^T + bias_e) ----------------------------
// Decode: xcd=bid&7, local=bid>>3; m-tile = xcd*32 + local/ntt; sub=local%ntt;
// expert = sub>>2 (pointer strides), n-tile = sub&3. Gating expert = eBase + expert.
// mode 0: Hout_e = v (bf16); mode 1: Out = wv*v; mode 2: Out += wv*v (wv>0, single-writer);
// mode 3: unsafeAtomicAdd(Out, wv*v) (wv>0; Out must be pre-zeroed; device-scope fp32).
template <bool A2F32>
__global__ void __launch_bounds__(256) gemm_kernel(
    const u16* __restrict__ A1, const u16* __restrict__ A2b, const float* __restrict__ A2f,
    size_t sA, const u16* __restrict__ Bt, size_t sBt,
    const float* __restrict__ bias, size_t sBias,
    u16* __restrict__ Hout, size_t sH, float* __restrict__ Out,
    const float* __restrict__ wg, int mode, int eBase, int ntt) {
    __shared__ u16 lds[A2F32 ? 12288 : 8192];
    u16* ldsA = lds;
    float* ldsF = (float*)lds;
    u16* ldsB = lds + (A2F32 ? 8192 : 4096);
    const int tid = threadIdx.x;
    const int lane = tid & 63;
    const int w = tid >> 6;

    const int bid = blockIdx.x;
    const int xcd = bid & 7;
    const int local = bid >> 3;
    const int mtl = local / ntt;
    const int sub = local - mtl * ntt;
    const int expert = sub >> 2;
    const int wgE = eBase + expert;
    const int m0 = (xcd * 32 + mtl) * 128;
    const int n0 = (sub & 3) * 128;

    const u16* A1p = A1 + (size_t)expert * sA;
    const u16* A2p = A2b + (size_t)expert * sA;
    const u16* Btp = Bt + (size_t)expert * sBt;
    const float* biasp = bias + (size_t)expert * sBias;
    u16* Houtp = Hout + (size_t)expert * sH;

    const int wm = (w >> 1) * 64;
    const int wn = (w & 1) * 64;

    f32x4 acc[4][4];
#pragma unroll
    for (int i = 0; i < 4; ++i)
#pragma unroll
        for (int j = 0; j < 4; ++j) acc[i][j] = (f32x4){0.f, 0.f, 0.f, 0.f};

    const int p0 = tid, p1 = 256 + tid;
    const int r0 = p0 >> 2, c0 = ((p0 & 3) - (r0 >> 1)) & 3;
    const int r1 = p1 >> 2, c1 = ((p1 & 3) - (r1 >> 1)) & 3;
    const int arow = lane & 15;
    const int kc = lane >> 4;

    for (int kb = 0; kb < 32; ++kb) {
        __syncthreads();
        if (!A2F32 || kb < 16) {
            const u16* As = (kb < 16) ? A1p : A2p;
            const int kcol = (kb & 15) * 32;
            gload16(As + (size_t)(m0 + r0) * DD + kcol + c0 * 8, ldsA + p0 * 8);
            gload16(As + (size_t)(m0 + r1) * DD + kcol + c1 * 8, ldsA + p1 * 8);
        } else {
            const float* Af = A2f + (size_t)m0 * DD + (kb - 16) * 32;
#pragma unroll
            for (int q = 0; q < 4; ++q) {
                int p = q * 256 + tid;
                int rr = p >> 3, cpos = p & 7, cc2 = (cpos - rr) & 7;
                gload16(Af + (size_t)rr * DD + cc2 * 4, ldsF + p * 4);
            }
        }
        gload16(Btp + (size_t)(n0 + r0) * 1024 + kb * 32 + c0 * 8, ldsB + p0 * 8);
        gload16(Btp + (size_t)(n0 + r1) * 1024 + kb * 32 + c1 * 8, ldsB + p1 * 8);
        __syncthreads();
        s16x8 af[4], bf[4];
        if (!A2F32 || kb < 16) {
#pragma unroll
            for (int f = 0; f < 4; ++f) {
                int ra = wm + f * 16 + arow;
                int pa = (kc + (ra >> 1)) & 3;
                af[f] = *(const s16x8*)(ldsA + (ra * 4 + pa) * 8);
            }
        } else {
#pragma unroll
            for (int f = 0; f < 4; ++f) {
                int ra = wm + f * 16 + arow;
                int plo = ra * 8 + ((2 * kc + ra) & 7);
                int phi = ra * 8 + ((2 * kc + 1 + ra) & 7);
                f32x4 lo = *(const f32x4*)(ldsF + plo * 4);
                f32x4 hi = *(const f32x4*)(ldsF + phi * 4);
                s16x8 t;
                t[0] = (short)f2b(lo[0]); t[1] = (short)f2b(lo[1]);
                t[2] = (short)f2b(lo[2]); t[3] = (short)f2b(lo[3]);
                t[4] = (short)f2b(hi[0]); t[5] = (short)f2b(hi[1]);
                t[6] = (short)f2b(hi[2]); t[7] = (short)f2b(hi[3]);
                af[f] = t;
            }
        }
#pragma unroll
        for (int f = 0; f < 4; ++f) {
            int rb = wn + f * 16 + arow;
            int pb = (kc + (rb >> 1)) & 3;
            bf[f] = *(const s16x8*)(ldsB + (rb * 4 + pb) * 8);
        }
#pragma unroll
        for (int i = 0; i < 4; ++i)
#pragma unroll
            for (int j = 0; j < 4; ++j)
                acc[i][j] = __builtin_amdgcn_mfma_f32_16x16x32_bf16(af[i], bf[j], acc[i][j], 0, 0, 0);
    }

    const int colq = lane & 15;
    const int rq = lane >> 4;
#pragma unroll
    for (int i = 0; i < 4; ++i) {
#pragma unroll
        for (int j = 0; j < 4; ++j) {
            int col = n0 + wn + j * 16 + colq;
            float bv = biasp[col];
#pragma unroll
            for (int r = 0; r < 4; ++r) {
                int row = m0 + wm + i * 16 + rq * 4 + r;
                float v = fmaxf(acc[i][j][r] + bv, 0.f);
                size_t idx = (size_t)row * DD + col;
                if (mode == 0) {
                    Houtp[idx] = f2b(v);
                } else {
                    float wv = wg[(size_t)row * 4 + wgE];
                    if (mode == 1) {
                        Out[idx] = wv * v;
                    } else if (mode == 2) {
                        if (wv > 0.f) Out[idx] += wv * v;
                    } else {
                        if (wv > 0.f) unsafeAtomicAdd(&Out[idx], wv * v);
                    }
                }
            }
        }
    }
}

extern "C" void kernel_launch(void* const* d_in, const int* in_sizes, int n_in,
                              void* d_out, int out_size, void* d_ws, size_t ws_size,
                              hipStream_t stream) {
    const float* x  = (const float*)d_in[0];
    const float* gW = (const float*)d_in[1];
    const float* gb = (const float*)d_in[2];
    const float* Wl = (const float*)d_in[3];
    const float* bl = (const float*)d_in[4];
    const float* Wr = (const float*)d_in[5];
    const u32*   ei = (const u32*)d_in[6];
    float* outp = (float*)d_out;

    char* ws = (char*)d_ws;
    size_t off = 0;
    auto alloc = [&](size_t bytes) -> void* {
        void* p = ws + off;
        off += (bytes + 255) & ~(size_t)255;
        return p;
    };
    const size_t MB32 = (size_t)NN * DD * 2;
    const size_t STR = (size_t)NN * DD;      // per-expert element stride
    int*   flags  = (int*)alloc(512);
    float* wg     = (float*)alloc((size_t)NN * 4 * 4);
    int*   deg    = (int*)alloc((size_t)NN * 4);
    int*   start  = (int*)alloc((size_t)NN * 4);
    int*   cursor = (int*)alloc((size_t)NN * 4);
    float* invd   = (float*)alloc((size_t)NN * 4);
    int*   src32  = (int*)alloc((size_t)EE * 4);
    int*   dst32  = (int*)alloc((size_t)EE * 4);
    int*   csr    = (int*)alloc((size_t)EE * 4);
    u16*   Bt     = (u16*)alloc((size_t)8 * WMAT * 2);       // 8 MB

    size_t rem = (ws_size > off) ? ws_size - off : 0;
    // tiers (beyond ~12 MB base):
    // 0: xb + h1[4] + aggr1[4]  (288 MB)  full-fused L1 (atomic), fused aggr x4
    // 1: xb + h1[4] + aggr1[2]  (224 MB)  pair-fused L1 (atomic), fused aggr x2
    // 2: xb + h1[4] + aggr1[1]  (192 MB)  bf16 fused L0, sequential L1
    // 3: aggr0 + h1[4]          (160 MB)  round-6 proven (fp32-staged fused L0)
    // 4: aggr0 + xb + h1 + aggr1 (128 MB) round-3 proven sequential
    // 5: aggr0 + h1 + aggr1     (96 MB)   fp32 fallback
    int tier;
    if      (rem >= 9 * MB32 + 65536) tier = 0;
    else if (rem >= 7 * MB32 + 65536) tier = 1;
    else if (rem >= 6 * MB32 + 65536) tier = 2;
    else if (rem >= 5 * MB32 + 65536) tier = 3;
    else if (rem >= 4 * MB32 + 65536) tier = 4;
    else                              tier = 5;

    u16 *xb = nullptr, *h1 = nullptr, *aggr1 = nullptr, *aggr0 = nullptr;
    if (tier <= 2) {
        xb = (u16*)alloc(MB32);
        h1 = (u16*)alloc(4 * MB32);
        aggr1 = (u16*)alloc((tier == 0 ? 4 : tier == 1 ? 2 : 1) * MB32);
        aggr0 = aggr1;                      // aggr0 dead after fused L0; aliases aggr1[0]
    } else if (tier == 3) {
        aggr0 = (u16*)alloc(MB32);
        h1 = (u16*)alloc(4 * MB32);
        aggr1 = aggr0;
    } else if (tier == 4) {
        aggr0 = (u16*)alloc(MB32);
        xb = (u16*)alloc(MB32);
        h1 = (u16*)alloc(MB32);
        aggr1 = (u16*)alloc(MB32);
    } else {
        aggr0 = (u16*)alloc(MB32);
        h1 = (u16*)alloc(MB32);
        aggr1 = (u16*)alloc(MB32);
    }

    int* bsum = flags + 16;
    int* boff = flags + 64;

    hipMemsetAsync(deg, 0, (size_t)NN * 4, stream);

    detect_kernel<<<1, 64, 0, stream>>>(ei, flags);
    edges_kernel<<<EE / 256, 256, 0, stream>>>(ei, flags, src32, dst32);
    transpose_kernel<<<16 * 256, 256, 0, stream>>>(Wl, Wr, Bt);
    gate_kernel<<<NN / 4, 256, 0, stream>>>(x, gW, gb, wg);
    deg_kernel<<<EE / 256, 256, 0, stream>>>(dst32, deg);
    scan1_kernel<<<32, 1024, 0, stream>>>(deg, start, invd, bsum);
    scan2_kernel<<<1, 64, 0, stream>>>(bsum, boff);
    scan3_kernel<<<NN / 256, 256, 0, stream>>>(start, cursor, boff);
    scatter_kernel<<<EE / 256, 256, 0, stream>>>(src32, dst32, cursor, csr);

    if (tier <= 2) {
        // -------- bf16 path: convert x once; all-bf16 fused L0 (no LDS conflicts) --------
        convert_kernel<<<NN * DD / 8 / 256, 256, 0, stream>>>(x, xb);
        aggr_kernel<false><<<8192, 256, 0, stream>>>(xb, aggr0, start, deg, csr, invd,
                                                     nullptr, 0, 0);
        gemm_kernel<false><<<256 * 16, 256, 0, stream>>>(
            aggr0, xb, nullptr, /*sA=*/0, Bt, /*sBt=*/2 * WMAT, bl, /*sBias=*/1024,
            h1, /*sH=*/STR, nullptr, wg, /*mode=*/0, /*eBase=*/0, /*ntt=*/16);
        if (tier == 0) {
            hipMemsetAsync(outp, 0, (size_t)NN * DD * 4, stream);
            aggr_kernel<false><<<4 * 8192, 256, 0, stream>>>(h1, aggr1, start, deg, csr,
                                                             invd, wg, 0, STR);
            gemm_kernel<false><<<256 * 16, 256, 0, stream>>>(
                aggr1, h1, nullptr, STR, Bt + WMAT, 2 * WMAT, bl + 512, 1024,
                nullptr, 0, outp, wg, /*mode=*/3, /*eBase=*/0, /*ntt=*/16);
        } else if (tier == 1) {
            hipMemsetAsync(outp, 0, (size_t)NN * DD * 4, stream);
            for (int p = 0; p < 2; ++p) {
                aggr_kernel<false><<<2 * 8192, 256, 0, stream>>>(
                    h1 + (size_t)2 * p * STR, aggr1, start, deg, csr, invd, wg, 2 * p, STR);
                gemm_kernel<false><<<256 * 8, 256, 0, stream>>>(
                    aggr1, h1 + (size_t)2 * p * STR, nullptr, STR,
                    Bt + WMAT + (size_t)2 * p * 2 * WMAT, 2 * WMAT,
                    bl + 512 + 2 * p * 1024, 1024,
                    nullptr, 0, outp, wg, /*mode=*/3, /*eBase=*/2 * p, /*ntt=*/8);
            }
        } else {
            for (int e = 0; e < 4; ++e) {
                aggr_kernel<false><<<8192, 256, 0, stream>>>(
                    h1 + (size_t)e * STR, aggr1, start, deg, csr, invd, wg, e, 0);
                gemm_kernel<false><<<256 * 4, 256, 0, stream>>>(
                    aggr1, h1 + (size_t)e * STR, nullptr, 0,
                    Bt + (size_t)(e * 2 + 1) * WMAT, 0, bl + (e * 2 + 1) * 512, 0,
                    nullptr, 0, outp, wg, (e == 0) ? 1 : 2, e, 4);
            }
        }
    } else if (tier == 3) {
        // -------- round-6 proven: fp32-staged fused L0, sequential L1 --------------------
        aggr_kernel<true><<<8192, 256, 0, stream>>>(x, aggr0, start, deg, csr, invd,
                                                    nullptr, 0, 0);
        gemm_kernel<true><<<256 * 16, 256, 0, stream>>>(
            aggr0, nullptr, x, 0, Bt, 2 * WMAT, bl, 1024,
            h1, STR, nullptr, wg, 0, 0, 16);
        for (int e = 0; e < 4; ++e) {
            aggr_kernel<false><<<8192, 256, 0, stream>>>(
                h1 + (size_t)e * STR, aggr1, start, deg, csr, invd, wg, e, 0);
            gemm_kernel<false><<<256 * 4, 256, 0, stream>>>(
                aggr1, h1 + (size_t)e * STR, nullptr, 0,
                Bt + (size_t)(e * 2 + 1) * WMAT, 0, bl + (e * 2 + 1) * 512, 0,
                nullptr, 0, outp, wg, (e == 0) ? 1 : 2, e, 4);
        }
    } else {
        // -------- round-3 proven sequential ----------------------------------------------
        if (tier == 4) {
            convert_kernel<<<NN * DD / 8 / 256, 256, 0, stream>>>(x, xb);
            aggr_kernel<false><<<8192, 256, 0, stream>>>(xb, aggr0, start, deg, csr, invd,
                                                         nullptr, 0, 0);
        } else {
            aggr_kernel<true><<<8192, 256, 0, stream>>>(x, aggr0, start, deg, csr, invd,
                                                        nullptr, 0, 0);
        }
        for (int e = 0; e < 4; ++e) {
            const u16* BtL0 = Bt + (size_t)(e * 2 + 0) * WMAT;
            const u16* BtL1 = Bt + (size_t)(e * 2 + 1) * WMAT;
            const float* b0 = bl + (e * 2 + 0) * 512;
            const float* b1 = bl + (e * 2 + 1) * 512;
            if (tier == 4)
                gemm_kernel<false><<<256 * 4, 256, 0, stream>>>(
                    aggr0, xb, nullptr, 0, BtL0, 0, b0, 0, h1, 0, nullptr, wg, 0, e, 4);
            else
                gemm_kernel<true><<<256 * 4, 256, 0, stream>>>(
                    aggr0, nullptr, x, 0, BtL0, 0, b0, 0, h1, 0, nullptr, wg, 0, e, 4);
            aggr_kernel<false><<<8192, 256, 0, stream>>>(h1, aggr1, start, deg, csr, invd,
                                                         wg, e, 0);
            gemm_kernel<false><<<256 * 4, 256, 0, stream>>>(
                aggr1, h1, nullptr, 0, BtL1, 0, b1, 0, nullptr, 0, outp, wg,
                (e == 0) ? 1 : 2, e, 4);
        }
    }
}